// Round 1
// baseline (9717.555 us; speedup 1.0000x reference)
//
#include <hip/hip_runtime.h>
#include <hip/hip_bf16.h>
#include <math.h>

#define BB 64
#define TT 200
#define DD 256
#define HH 512
#define NCOL 3584  // 7*H

__device__ __forceinline__ float sigmoidf_(float x) {
    return 1.0f / (1.0f + expf(-x));
}
__device__ __forceinline__ float softplusf_(float x) {
    return fmaxf(x, 0.0f) + log1pf(expf(-fabsf(x)));
}

// durT[t*B + b] = dur[b*T + t]
__global__ __launch_bounds__(256) void transpose_dur_kernel(
    const float* __restrict__ dur, float* __restrict__ durT)
{
    int idx = blockIdx.x * 256 + threadIdx.x;
    if (idx < BB * TT) {
        int t = idx >> 6;   // idx / 64
        int b = idx & 63;
        durT[idx] = dur[b * TT + t];
    }
}

// Xb[t][col][b] = sum_d input[b][t][d] * Wx[d][col] + bias[col]
// grid: (NCOL/64, T), block: 256 threads
__global__ __launch_bounds__(256) void precompute_kernel(
    const float* __restrict__ input, const float* __restrict__ Wx,
    const float* __restrict__ bias, float* __restrict__ Xb)
{
    __shared__ float in_lds[DD * 65];  // [d][b] padded, 66.5 KB

    const int tid = threadIdx.x;
    const int t = blockIdx.y;
    const int c0 = blockIdx.x * 64;
    const int b = tid & 63;
    const int cq = tid >> 6;  // 0..3

    // stage input[:, t, :] into LDS transposed: in_lds[d*65 + b]
    #pragma unroll
    for (int it = 0; it < 16; ++it) {
        int idx4 = it * 256 + tid;       // 0..4095
        int b_ = idx4 >> 6;              // 0..63
        int d4 = idx4 & 63;              // 0..63
        const float4 v = *(const float4*)(input + ((size_t)b_ * TT + t) * DD + d4 * 4);
        in_lds[(d4 * 4 + 0) * 65 + b_] = v.x;
        in_lds[(d4 * 4 + 1) * 65 + b_] = v.y;
        in_lds[(d4 * 4 + 2) * 65 + b_] = v.z;
        in_lds[(d4 * 4 + 3) * 65 + b_] = v.w;
    }
    __syncthreads();

    float acc[16];
    #pragma unroll
    for (int i = 0; i < 16; ++i) acc[i] = 0.0f;

    const int cbase = c0 + cq * 16;
    const float* __restrict__ wxp = Wx + cbase;

    for (int d = 0; d < DD; ++d) {
        const float hv = in_lds[d * 65 + b];
        const float* wr = wxp + (size_t)d * NCOL;
        #pragma unroll
        for (int i = 0; i < 16; ++i) acc[i] = fmaf(hv, wr[i], acc[i]);
    }

    float* __restrict__ outp = Xb + (size_t)t * NCOL * BB + (size_t)cbase * BB + b;
    #pragma unroll
    for (int i = 0; i < 16; ++i) {
        outp[i * BB] = acc[i] + bias[cbase + i];
    }
}

// One recurrent step. grid: 256 blocks (j-strips of 2), block: 256 threads.
// Thread (b, jq, kh): accumulates 7 gate dot-products over K-half, LDS-reduce,
// kh==0 threads do gates + state update + write outputs + next-h precompute.
__global__ __launch_bounds__(256) void step_kernel(
    const float* __restrict__ Xb,     // (T, NCOL, B)
    const float* __restrict__ Wh,     // (H, NCOL)
    const float* __restrict__ durT,   // (T, B)
    const float* __restrict__ hT_in,  // (H, B)
    float* __restrict__ hT_out,       // (H, B)
    float* __restrict__ cdec,         // (H, B)  decayed cell c_t^dec
    float* __restrict__ cbar,         // (H, B)
    float* __restrict__ out,          // (4, B, T, H)
    int t)
{
    const int tid = threadIdx.x;
    const int b = tid & 63;
    const int sub = tid >> 6;   // 0..3
    const int jq = sub & 1;     // 0..1
    const int kh = sub >> 1;    // 0..1
    const int j = blockIdx.x * 2 + jq;  // 0..511

    float acc[7];
    #pragma unroll
    for (int g = 0; g < 7; ++g) acc[g] = 0.0f;

    {
        const float* __restrict__ hp = hT_in + (kh * 256) * BB + b;
        const float* __restrict__ wp = Wh + (size_t)(kh * 256) * NCOL + j;
        #pragma unroll 4
        for (int d = 0; d < 256; ++d) {
            const float hv = hp[d * BB];
            const float* wr = wp + (size_t)d * NCOL;
            #pragma unroll
            for (int g = 0; g < 7; ++g) acc[g] = fmaf(hv, wr[g * HH], acc[g]);
        }
    }

    __shared__ float red[2 * 7 * 64];
    if (kh == 1) {
        #pragma unroll
        for (int g = 0; g < 7; ++g) red[(jq * 7 + g) * 64 + b] = acc[g];
    }
    __syncthreads();

    if (kh == 0) {
        const float* __restrict__ xb = Xb + (size_t)t * NCOL * BB + b;
        #pragma unroll
        for (int g = 0; g < 7; ++g) {
            acc[g] += red[(jq * 7 + g) * 64 + b];
            acc[g] += xb[(size_t)(g * HH + j) * BB];
        }

        const float i_  = sigmoidf_(acc[0]);
        const float f_  = sigmoidf_(acc[1]);
        const float z_  = tanhf(acc[2]);
        const float o_  = sigmoidf_(acc[3]);
        const float ib_ = sigmoidf_(acc[4]);
        const float fb_ = sigmoidf_(acc[5]);
        const float d_  = softplusf_(acc[6]);

        const int hb = j * BB + b;
        const float cd = cdec[hb];
        const float cb = cbar[hb];
        const float c_new  = f_ * cd + i_ * z_;
        const float cb_new = fb_ * cb + ib_ * z_;

        const size_t sstride = (size_t)BB * TT * HH;
        const size_t obase = ((size_t)b * TT + t) * HH + j;
        out[obase]               = c_new;
        out[obase + sstride]     = cb_new;
        out[obase + 2 * sstride] = d_;
        out[obase + 3 * sstride] = o_;

        if (t + 1 < TT) {
            const float dt = durT[(t + 1) * BB + b];
            const float cdn = cb_new + (c_new - cb_new) * expf(-d_ * dt);
            const float hn = o_ * tanhf(cdn);
            cdec[hb] = cdn;
            cbar[hb] = cb_new;
            hT_out[hb] = hn;
        }
    }
}

extern "C" void kernel_launch(void* const* d_in, const int* in_sizes, int n_in,
                              void* d_out, int out_size, void* d_ws, size_t ws_size,
                              hipStream_t stream) {
    const float* input = (const float*)d_in[0];  // (B, T, D)
    const float* dur   = (const float*)d_in[1];  // (B, T)
    const float* Wx    = (const float*)d_in[2];  // (D, 7H)
    const float* Wh    = (const float*)d_in[3];  // (H, 7H)
    const float* bias  = (const float*)d_in[4];  // (7H,)
    float* out = (float*)d_out;                  // (4, B, T, H)

    float* ws = (float*)d_ws;
    float* Xb   = ws;                                  // T*NCOL*B
    float* hbuf = Xb + (size_t)TT * NCOL * BB;         // 2 * H*B
    float* cdec = hbuf + 2 * HH * BB;                  // H*B
    float* cbar = cdec + HH * BB;                      // H*B
    float* durT = cbar + HH * BB;                      // T*B

    // zero h0 + cdec + cbar (h1 fully written by step 0's epilogue)
    hipMemsetAsync(hbuf, 0, (size_t)4 * HH * BB * sizeof(float), stream);

    transpose_dur_kernel<<<(BB * TT + 255) / 256, 256, 0, stream>>>(dur, durT);
    precompute_kernel<<<dim3(NCOL / 64, TT), 256, 0, stream>>>(input, Wx, bias, Xb);

    for (int t = 0; t < TT; ++t) {
        step_kernel<<<HH / 2, 256, 0, stream>>>(
            Xb, Wh, durT,
            hbuf + (t & 1) * HH * BB,
            hbuf + ((t + 1) & 1) * HH * BB,
            cdec, cbar, out, t);
    }
}

// Round 2
// 2643.176 us; speedup vs baseline: 3.6765x; 3.6765x over previous
//
#include <hip/hip_runtime.h>
#include <hip/hip_bf16.h>
#include <math.h>

#define BB 64
#define TT 200
#define DD 256
#define HH 512
#define NCOL 3584  // 7*H

using bf16x8 = __attribute__((ext_vector_type(8))) short;
using f32x4  = __attribute__((ext_vector_type(4))) float;

__device__ __forceinline__ float sigmoidf_(float x) {
    return 1.0f / (1.0f + expf(-x));
}
__device__ __forceinline__ float softplusf_(float x) {
    return fmaxf(x, 0.0f) + log1pf(expf(-fabsf(x)));
}
__device__ __forceinline__ short f2bf(float f) {
    union { float f; unsigned u; } v; v.f = f;
    unsigned r = v.u + 0x7fff + ((v.u >> 16) & 1);  // RNE
    return (short)(r >> 16);
}
__device__ __forceinline__ float bf2f(short s) {
    union { unsigned u; float f; } v; v.u = ((unsigned)(unsigned short)s) << 16;
    return v.f;
}

// input (B,T,D) fp32 -> Xbf (B*T, D) bf16, 4 elems/thread
__global__ __launch_bounds__(256) void convert_x_kernel(
    const float* __restrict__ in, short* __restrict__ Xbf)
{
    int idx = blockIdx.x * 256 + threadIdx.x;  // < 819200
    float4 v = ((const float4*)in)[idx];
    short4 s;
    s.x = f2bf(v.x); s.y = f2bf(v.y); s.z = f2bf(v.z); s.w = f2bf(v.w);
    ((short4*)Xbf)[idx] = s;
}

// Wx (D, NCOL) fp32 -> WxP packed B-fragments:
// WxP[((nt*8 + kt)*64 + lane)*8 + jj] = bf16(Wx[k][nt*16 + (lane&15)]),
//   k = kt*32 + (lane>>4)*8 + jj
__global__ __launch_bounds__(256) void pack_wx_kernel(
    const float* __restrict__ Wx, short* __restrict__ WxP)
{
    int idx = blockIdx.x * 256 + threadIdx.x;  // < 224*8*64*8 = 917504
    int jj = idx & 7, lane = (idx >> 3) & 63, kt = (idx >> 9) & 7, nt = idx >> 12;
    int k = kt * 32 + ((lane >> 4) << 3) + jj;
    int col = nt * 16 + (lane & 15);
    WxP[idx] = f2bf(Wx[(size_t)k * NCOL + col]);
}

// Wh (H, NCOL) fp32 -> WhP packed B-fragments grouped per (j0, gate):
// WhP[(((j0*7+g)*16 + kt)*64 + lane)*8 + jj] = bf16(Wh[k][g*512 + j0*16 + (lane&15)])
__global__ __launch_bounds__(256) void pack_wh_kernel(
    const float* __restrict__ Wh, short* __restrict__ WhP)
{
    int idx = blockIdx.x * 256 + threadIdx.x;  // < 32*7*16*64*8 = 1835008
    int jj = idx & 7, lane = (idx >> 3) & 63, kt = (idx >> 9) & 15;
    int gj = idx >> 13;  // j0*7 + g
    int g = gj % 7, j0 = gj / 7;
    int k = kt * 32 + ((lane >> 4) << 3) + jj;
    int col = g * HH + j0 * 16 + (lane & 15);
    WhP[idx] = f2bf(Wh[(size_t)k * NCOL + col]);
}

// GEMM1: Xb[row][col] = bf16( Xbf(row,:) @ Wx(:,col) + bias[col] )
// grid (56, 200), block 256 (4 waves). Wave w: m-tile w; 4 n-tiles per block.
__global__ __launch_bounds__(256) void precompute_kernel(
    const short* __restrict__ Xbf, const short* __restrict__ WxP,
    const float* __restrict__ bias, short* __restrict__ Xb)
{
    const int tid = threadIdx.x;
    const int lane = tid & 63;
    const int w = tid >> 6;
    const int nb = blockIdx.x;   // 0..55
    const int mb = blockIdx.y;   // 0..199

    f32x4 acc[4];
    #pragma unroll
    for (int i = 0; i < 4; ++i) acc[i] = (f32x4){0.f, 0.f, 0.f, 0.f};

    const int rowA = mb * 64 + w * 16 + (lane & 15);
    const short* __restrict__ ha = Xbf + (size_t)rowA * DD + ((lane >> 4) << 3);
    const short* __restrict__ wbase = WxP + ((size_t)(nb * 4) * 512 + lane) * 8;
    // nt stride = 8*64*8 = 4096 elems; kt stride = 64*8 = 512 elems

    #pragma unroll 2
    for (int kt = 0; kt < 8; ++kt) {
        bf16x8 a = *(const bf16x8*)(ha + kt * 32);
        #pragma unroll
        for (int i = 0; i < 4; ++i) {
            bf16x8 b = *(const bf16x8*)(wbase + i * 4096 + kt * 512);
            acc[i] = __builtin_amdgcn_mfma_f32_16x16x32_bf16(a, b, acc[i], 0, 0, 0);
        }
    }

    const int colL = lane & 15;
    const int rBase = mb * 64 + w * 16 + ((lane >> 4) << 2);
    #pragma unroll
    for (int i = 0; i < 4; ++i) {
        const int col = (nb * 4 + i) * 16 + colL;
        const float bv = bias[col];
        #pragma unroll
        for (int r = 0; r < 4; ++r) {
            Xb[(size_t)(rBase + r) * NCOL + col] = f2bf(acc[i][r] + bv);
        }
    }
}

// One recurrent step, fully fused. grid 32 blocks (16 h-cols each), 256 thr.
// Wave w handles batches w*16..w*16+15; 7 acc frags = 7 gates for the
// block's 16 h-columns. Epilogue is per-lane local (gates of a (b,hcol)
// pair all live in the same lane/reg).
__global__ __launch_bounds__(256) void step_kernel(
    const short* __restrict__ Xb,    // (B*T, NCOL) bf16
    const short* __restrict__ WhP,   // packed
    const float* __restrict__ dur,   // (B, T)
    const short* __restrict__ h_in,  // (B, H) bf16
    short* __restrict__ h_out,       // (B, H) bf16
    float* __restrict__ cdec,        // (B, H)
    float* __restrict__ cbar,        // (B, H)
    float* __restrict__ out,         // (4, B, T, H)
    int t)
{
    const int tid = threadIdx.x;
    const int lane = tid & 63;
    const int w = tid >> 6;      // m-tile (batch group)
    const int j0 = blockIdx.x;   // 0..31

    f32x4 acc[7];
    #pragma unroll
    for (int g = 0; g < 7; ++g) acc[g] = (f32x4){0.f, 0.f, 0.f, 0.f};

    const int rowA = w * 16 + (lane & 15);
    const short* __restrict__ ha = h_in + (size_t)rowA * HH + ((lane >> 4) << 3);
    const short* __restrict__ wb = WhP + ((size_t)(j0 * 7) * 1024 + lane) * 8;
    // g stride = 16*64*8 = 8192 elems; kt stride = 64*8 = 512 elems

    #pragma unroll 2
    for (int kt = 0; kt < 16; ++kt) {
        bf16x8 a = *(const bf16x8*)(ha + kt * 32);
        const short* wkt = wb + kt * 512;
        #pragma unroll
        for (int g = 0; g < 7; ++g) {
            bf16x8 b = *(const bf16x8*)(wkt + g * 8192);
            acc[g] = __builtin_amdgcn_mfma_f32_16x16x32_bf16(a, b, acc[g], 0, 0, 0);
        }
    }

    const int colL = lane & 15;
    const int hcol = j0 * 16 + colL;
    const int bBase = w * 16 + ((lane >> 4) << 2);
    const size_t S = (size_t)BB * TT * HH;

    #pragma unroll
    for (int r = 0; r < 4; ++r) {
        const int b = bBase + r;
        const short* xrow = Xb + ((size_t)b * TT + t) * NCOL + hcol;
        const float gi  = acc[0][r] + bf2f(xrow[0 * HH]);
        const float gf  = acc[1][r] + bf2f(xrow[1 * HH]);
        const float gz  = acc[2][r] + bf2f(xrow[2 * HH]);
        const float go  = acc[3][r] + bf2f(xrow[3 * HH]);
        const float gib = acc[4][r] + bf2f(xrow[4 * HH]);
        const float gfb = acc[5][r] + bf2f(xrow[5 * HH]);
        const float gd  = acc[6][r] + bf2f(xrow[6 * HH]);

        const float i_  = sigmoidf_(gi);
        const float f_  = sigmoidf_(gf);
        const float z_  = tanhf(gz);
        const float o_  = sigmoidf_(go);
        const float ib_ = sigmoidf_(gib);
        const float fb_ = sigmoidf_(gfb);
        const float d_  = softplusf_(gd);

        const int hb = b * HH + hcol;
        const float cd = cdec[hb];
        const float cb = cbar[hb];
        const float c_new  = f_ * cd + i_ * z_;
        const float cb_new = fb_ * cb + ib_ * z_;

        const size_t ob = ((size_t)b * TT + t) * HH + hcol;
        out[ob]         = c_new;
        out[ob + S]     = cb_new;
        out[ob + 2 * S] = d_;
        out[ob + 3 * S] = o_;

        if (t + 1 < TT) {
            const float dt = dur[b * TT + t + 1];
            const float cdn = cb_new + (c_new - cb_new) * expf(-d_ * dt);
            const float hn = o_ * tanhf(cdn);
            cdec[hb] = cdn;
            cbar[hb] = cb_new;
            h_out[hb] = f2bf(hn);
        }
    }
}

extern "C" void kernel_launch(void* const* d_in, const int* in_sizes, int n_in,
                              void* d_out, int out_size, void* d_ws, size_t ws_size,
                              hipStream_t stream) {
    const float* input = (const float*)d_in[0];  // (B, T, D)
    const float* dur   = (const float*)d_in[1];  // (B, T)
    const float* Wx    = (const float*)d_in[2];  // (D, 7H)
    const float* Wh    = (const float*)d_in[3];  // (H, 7H)
    const float* bias  = (const float*)d_in[4];  // (7H,)
    float* out = (float*)d_out;                  // (4, B, T, H)

    short* Xb  = (short*)d_ws;                       // 45,875,200 ele bf16
    short* Xbf = Xb + (size_t)TT * BB * NCOL;        // 3,276,800 ele
    short* WxP = Xbf + (size_t)BB * TT * DD;         // 917,504 ele
    short* WhP = WxP + 224 * 8 * 64 * 8;             // 1,835,008 ele
    short* h0  = WhP + 32 * 7 * 16 * 64 * 8;         // 32,768 ele
    short* h1  = h0 + BB * HH;                       // 32,768 ele
    float* cdec = (float*)(h1 + BB * HH);            // 32,768 ele fp32
    float* cbar = cdec + BB * HH;                    // 32,768 ele fp32

    // zero h0, h1, cdec, cbar in one contiguous memset
    hipMemsetAsync(h0, 0, (size_t)2 * BB * HH * sizeof(short)
                          + (size_t)2 * BB * HH * sizeof(float), stream);

    convert_x_kernel<<<3200, 256, 0, stream>>>(input, Xbf);
    pack_wx_kernel<<<3584, 256, 0, stream>>>(Wx, WxP);
    pack_wh_kernel<<<7168, 256, 0, stream>>>(Wh, WhP);

    precompute_kernel<<<dim3(56, 200), 256, 0, stream>>>(Xbf, WxP, bias, Xb);

    short* hbufs[2] = {h0, h1};
    for (int t = 0; t < TT; ++t) {
        step_kernel<<<32, 256, 0, stream>>>(
            Xb, WhP, dur,
            hbufs[t & 1], hbufs[(t + 1) & 1],
            cdec, cbar, out, t);
    }
}